// Round 3
// baseline (2894.093 us; speedup 1.0000x reference)
//
#include <hip/hip_runtime.h>
#include <hip/hip_bf16.h>

// LSTM: B=16384, T=5, IN=11, H=512. Output = final cell state c [B,H] fp32.
//
// R3 changes vs R2 (which still spilled ~3.5 GB scratch; VGPR stuck at 128
// arch + AGPR split, arch demand ~184 > 128):
//  - re-tile: 1024 threads / 16 waves per block; each wave owns 32 rows x
//    64 cols (was 64x64). Per-wave arch state: cacc[32] + acc[2][4](->AGPR)
//    + A[2]/B[4] in flight + addressing ~= 100 < 128. No spills by
//    construction at the default 4-waves/EU budget.
//  - cost: each B fragment read by 2 row-half waves (2x L2 B traffic,
//    ~165 us L2 floor) -- irrelevant next to removing 3.5 GB of scratch.

#define HID   512
#define KDIM  544            // K extent: 512 h + 11 x + 1 bias + 20 zero pad
#define KROW  552            // LDS row stride in halves (bank rotation pad)
#define KSN   17             // KDIM / 32 MFMA K-steps
#define ROWS  64             // batch rows per block
#define BUFH  (ROWS * KROW)  // halfs per h buffer
#define NTHR  1024           // 16 waves
#define SMEM_HALFS (2 * BUFH + 64 * 56)
#define SMEM_BYTES (SMEM_HALFS * 2)

typedef _Float16 f16x8 __attribute__((ext_vector_type(8)));
typedef float f32x4 __attribute__((ext_vector_type(4)));

__device__ __forceinline__ float sigf(float x) {
    return 1.0f / (1.0f + __expf(-x));
}
__device__ __forceinline__ float tanh_fast(float x) {
    return 1.0f - 2.0f / (1.0f + __expf(2.0f * x));
}

// ---------------- prologue: pack W into B-fragment-ordered fp16 tiles -------
// Fragment (j 0..31, g 0..3, ks 0..16): lane l holds
// W[col = g*512 + j*16 + (l&15)][k = ks*32 + (l>>4)*8 .. +7], 16 B/lane.
__global__ void pack_w(const float* __restrict__ Wih, const float* __restrict__ Whh,
                       const float* __restrict__ bih, const float* __restrict__ bhh,
                       _Float16* __restrict__ Wt) {
    int tid  = blockIdx.x * 256 + threadIdx.x;
    int frag = tid >> 6;
    int lane = tid & 63;
    if (frag >= 32 * 4 * KSN) return;
    int ks = frag % KSN;
    int g  = (frag / KSN) & 3;
    int j  = frag / (KSN * 4);
    int col = g * 512 + j * 16 + (lane & 15);
    int kb  = ks * 32 + ((lane >> 4) << 3);
    _Float16 v[8];
#pragma unroll
    for (int q = 0; q < 8; q++) {
        int k = kb + q;
        float x;
        if (k < 512)      x = Whh[col * 512 + k];
        else if (k < 523) x = Wih[col * 11 + (k - 512)];
        else if (k == 523) x = bih[col] + bhh[col];
        else              x = 0.0f;
        v[q] = (_Float16)x;
    }
    *(f16x8*)(Wt + (size_t)frag * 512 + lane * 8) = *(const f16x8*)v;
}

// ---------------- one recurrent step ----------------------------------------
// Wave (rh, wc) handles rows rh*32..+31, col quads j = wc + ji*8 (ji 0..3).
// KS0=16: only the x/bias K-step (t=0 where h==0). WRITE_H=false at t=4.
template <int KS0, bool WRITE_H>
__device__ __forceinline__ void run_step(const _Float16* __restrict__ cur,
                                         _Float16* __restrict__ nxt,
                                         const _Float16* __restrict__ Wt,
                                         float* __restrict__ cacc,
                                         const int rh, const int wc, const int lane) {
    const int m  = lane & 15;
    const int kq = lane >> 4;
    const _Float16* abase = cur + (rh * 32 + m) * KROW + kq * 8;
#pragma unroll
    for (int ji = 0; ji < 4; ji++) {
        const int j = wc + ji * 8;                         // 0..31 col quad
        const f16x8* __restrict__ wp = (const f16x8*)(Wt + (size_t)j * 4 * KSN * 512);
        f32x4 acc[2][4];                                   // [row-tile][gate]
#pragma unroll
        for (int rt = 0; rt < 2; rt++)
#pragma unroll
            for (int g = 0; g < 4; g++) {
                f32x4 z = {0.f, 0.f, 0.f, 0.f};
                acc[rt][g] = z;
            }

#pragma unroll
        for (int ks = KS0; ks < KSN; ks++) {
            f16x8 A[2], B[4];
#pragma unroll
            for (int g = 0; g < 4; g++)
                B[g] = wp[(g * KSN + ks) * 64 + lane];
#pragma unroll
            for (int rt = 0; rt < 2; rt++)
                A[rt] = *(const f16x8*)(abase + rt * 16 * KROW + ks * 32);
#pragma unroll
            for (int rt = 0; rt < 2; rt++)
#pragma unroll
                for (int g = 0; g < 4; g++)
                    acc[rt][g] = __builtin_amdgcn_mfma_f32_16x16x32_f16(
                        A[rt], B[g], acc[rt][g], 0, 0, 0);
        }

        // gate nonlinearities; C/D layout: col = lane&15, row = (lane>>4)*4 + reg
#pragma unroll
        for (int rt = 0; rt < 2; rt++) {
#pragma unroll
            for (int r = 0; r < 4; r++) {
                float ig = acc[rt][0][r];
                float fg = acc[rt][1][r];
                float gg = acc[rt][2][r];
                float og = acc[rt][3][r];
                const int ci = ji * 8 + rt * 4 + r;
                float cn = sigf(fg) * cacc[ci] + sigf(ig) * tanh_fast(gg);
                cacc[ci] = cn;
                if (WRITE_H) {
                    float hn = sigf(og) * tanh_fast(cn);
                    nxt[(rh * 32 + rt * 16 + kq * 4 + r) * KROW + j * 16 + m] =
                        (_Float16)hn;
                }
            }
        }
    }
}

__device__ __forceinline__ void xfill(_Float16* __restrict__ nxt,
                                      const _Float16* __restrict__ xlds,
                                      int step, int tid) {
    for (int i = tid; i < 64 * 11; i += NTHR) {
        int row = i / 11, xi = i - row * 11;
        nxt[row * KROW + 512 + xi] = xlds[row * 56 + step * 11 + xi];
    }
}

// ---------------- main persistent kernel ------------------------------------
__global__ __launch_bounds__(NTHR, 4)
void lstm_main(const float* __restrict__ ts,
               const _Float16* __restrict__ Wt,
               float* __restrict__ out) {
    extern __shared__ _Float16 smem[];
    _Float16* hbuf = smem;             // 2 buffers of [64][KROW]
    _Float16* xlds = smem + 2 * BUFH;  // [64][56] fp16 copy of ts rows
    const int tid  = threadIdx.x;
    const int lane = tid & 63;
    const int wave = tid >> 6;         // 0..15
    const int rh   = wave >> 3;        // row half 0/1
    const int wc   = wave & 7;         // col group 0..7
    const int b0   = blockIdx.x * ROWS;

    // zero both h buffers (covers h cols, x cols, bias, pad cols)
    {
        f16x8 z = {(_Float16)0, (_Float16)0, (_Float16)0, (_Float16)0,
                   (_Float16)0, (_Float16)0, (_Float16)0, (_Float16)0};
        for (int i = tid * 8; i < 2 * BUFH; i += NTHR * 8)
            *(f16x8*)(smem + i) = z;
    }
    // stage this block's time_series rows (coalesced) as fp16
    for (int i = tid; i < 64 * 55; i += NTHR) {
        int row = i / 55, e = i - row * 55;
        xlds[row * 56 + e] = (_Float16)ts[(size_t)(b0 + row) * 55 + e];
    }
    __syncthreads();
    // bias column (k=523) = 1.0 in both buffers; x_0 into buffer 0
    if (tid < 128) {
        int bsel = tid >> 6, row = tid & 63;
        hbuf[bsel * BUFH + row * KROW + 523] = (_Float16)1.0f;
    }
    for (int i = tid; i < 64 * 11; i += NTHR) {
        int row = i / 11, xi = i - row * 11;
        hbuf[row * KROW + 512 + xi] = xlds[row * 56 + xi];
    }
    __syncthreads();

    float cacc[32];
#pragma unroll
    for (int i = 0; i < 32; i++) cacc[i] = 0.0f;

    // t = 0: h == 0, only the x/bias K-step contributes
    run_step<16, true>(hbuf, hbuf + BUFH, Wt, cacc, rh, wc, lane);
    xfill(hbuf + BUFH, xlds, 1, tid);
    __syncthreads();

    for (int t = 1; t < 4; t++) {
        const _Float16* cur = hbuf + (t & 1) * BUFH;
        _Float16* nxt       = hbuf + ((t + 1) & 1) * BUFH;
        run_step<0, true>(cur, nxt, Wt, cacc, rh, wc, lane);
        xfill(nxt, xlds, t + 1, tid);
        __syncthreads();
    }
    // t = 4: no h write needed
    run_step<0, false>(hbuf, hbuf + BUFH, Wt, cacc, rh, wc, lane);

    // write final c
    const int m = lane & 15, kq = lane >> 4;
#pragma unroll
    for (int ji = 0; ji < 4; ji++) {
        const int j = wc + ji * 8;
#pragma unroll
        for (int rt = 0; rt < 2; rt++)
#pragma unroll
            for (int r = 0; r < 4; r++)
                out[(size_t)(b0 + rh * 32 + rt * 16 + kq * 4 + r) * HID + j * 16 + m] =
                    cacc[ji * 8 + rt * 4 + r];
    }
}

extern "C" void kernel_launch(void* const* d_in, const int* in_sizes, int n_in,
                              void* d_out, int out_size, void* d_ws, size_t ws_size,
                              hipStream_t stream) {
    const float* ts  = (const float*)d_in[0];
    const float* Wih = (const float*)d_in[1];
    const float* Whh = (const float*)d_in[2];
    const float* bih = (const float*)d_in[3];
    const float* bhh = (const float*)d_in[4];
    float* out       = (float*)d_out;
    _Float16* Wt     = (_Float16*)d_ws;   // 32*4*17 frags x 1 KB = 2,228,224 B

    (void)in_sizes; (void)n_in; (void)out_size; (void)ws_size;

    hipFuncSetAttribute(reinterpret_cast<const void*>(lstm_main),
                        hipFuncAttributeMaxDynamicSharedMemorySize, SMEM_BYTES);

    pack_w<<<544, 256, 0, stream>>>(Wih, Whh, bih, bhh, Wt);
    lstm_main<<<256, NTHR, SMEM_BYTES, stream>>>(ts, Wt, out);
}

// Round 4
// 299.526 us; speedup vs baseline: 9.6622x; 9.6622x over previous
//
#include <hip/hip_runtime.h>
#include <hip/hip_bf16.h>

// LSTM: B=16384, T=5, IN=11, H=512. Output = final cell state c [B,H] fp32.
//
// R4 root-cause fix: R1-R3 all spilled GBs of scratch because the MFMA K-loop
// was fully unrolled (ji*ks*steps = 340 bodies); the scheduler hoisted whole
// batches of global/LDS loads across MFMAs, exploding live ranges. The fix is
// NOT smaller tiles (R3 proved that) -- it is bounding the loop:
//  - `#pragma unroll 1` on the ks loop, incremental pointer stepping.
//  - per-iteration in-flight: 4 B-frag (16 v) + 2 A-frag (8 v) + acc 32 (a)
//    + cacc 32 + addr ~16  => ~90 arch VGPRs < 128 @ 4 waves/EU. No spills.
// Tiling (from R3): 256 blocks x 64 rows; 16 waves/block; each wave owns
// 32 rows x 64 cols (2 row-tiles x 4 col-quads x 4 gates). B-frags stream
// global->VGPR from L2-resident packed W (2.2 MB); LDS serves only h.

#define HID   512
#define KDIM  544            // K extent: 512 h + 11 x + 1 bias + 20 zero pad
#define KROW  552            // LDS row stride in halves (bank rotation pad)
#define KSN   17             // KDIM / 32 MFMA K-steps
#define ROWS  64             // batch rows per block
#define BUFH  (ROWS * KROW)  // halfs per h buffer
#define NTHR  1024           // 16 waves
#define SMEM_HALFS (2 * BUFH + 64 * 56)
#define SMEM_BYTES (SMEM_HALFS * 2)

typedef _Float16 f16x8 __attribute__((ext_vector_type(8)));
typedef float f32x4 __attribute__((ext_vector_type(4)));

__device__ __forceinline__ float sigf(float x) {
    return 1.0f / (1.0f + __expf(-x));
}
__device__ __forceinline__ float tanh_fast(float x) {
    return 1.0f - 2.0f / (1.0f + __expf(2.0f * x));
}

// ---------------- prologue: pack W into B-fragment-ordered fp16 tiles -------
// Fragment (j 0..31, g 0..3, ks 0..16): lane l holds
// W[col = g*512 + j*16 + (l&15)][k = ks*32 + (l>>4)*8 .. +7], 16 B/lane.
__global__ void pack_w(const float* __restrict__ Wih, const float* __restrict__ Whh,
                       const float* __restrict__ bih, const float* __restrict__ bhh,
                       _Float16* __restrict__ Wt) {
    int tid  = blockIdx.x * 256 + threadIdx.x;
    int frag = tid >> 6;
    int lane = tid & 63;
    if (frag >= 32 * 4 * KSN) return;
    int ks = frag % KSN;
    int g  = (frag / KSN) & 3;
    int j  = frag / (KSN * 4);
    int col = g * 512 + j * 16 + (lane & 15);
    int kb  = ks * 32 + ((lane >> 4) << 3);
    _Float16 v[8];
#pragma unroll
    for (int q = 0; q < 8; q++) {
        int k = kb + q;
        float x;
        if (k < 512)      x = Whh[col * 512 + k];
        else if (k < 523) x = Wih[col * 11 + (k - 512)];
        else if (k == 523) x = bih[col] + bhh[col];
        else              x = 0.0f;
        v[q] = (_Float16)x;
    }
    *(f16x8*)(Wt + (size_t)frag * 512 + lane * 8) = *(const f16x8*)v;
}

// ---------------- one recurrent step ----------------------------------------
// Wave (rh, wc) handles rows rh*32..+31, col quads j = wc + ji*8 (ji 0..3).
// KS0=16: only the x/bias K-step (t=0 where h==0). WRITE_H=false at t=4.
template <int KS0, bool WRITE_H>
__device__ __forceinline__ void run_step(const _Float16* __restrict__ cur,
                                         _Float16* __restrict__ nxt,
                                         const _Float16* __restrict__ Wt,
                                         float* __restrict__ cacc,
                                         const int rh, const int wc, const int lane) {
    const int m  = lane & 15;
    const int kq = lane >> 4;
    const _Float16* abase0 = cur + (rh * 32 + m) * KROW + kq * 8 + KS0 * 32;
#pragma unroll
    for (int ji = 0; ji < 4; ji++) {
        const int j = wc + ji * 8;                         // 0..31 col quad
        const f16x8* __restrict__ bptr =
            (const f16x8*)(Wt + (size_t)j * 4 * KSN * 512) + KS0 * 64 + lane;
        const _Float16* aptr = abase0;
        f32x4 acc[2][4];                                   // [row-tile][gate]
#pragma unroll
        for (int rt = 0; rt < 2; rt++)
#pragma unroll
            for (int g = 0; g < 4; g++) {
                f32x4 z = {0.f, 0.f, 0.f, 0.f};
                acc[rt][g] = z;
            }

#pragma unroll 1                           // REAL loop: bounded live ranges
        for (int ks = KS0; ks < KSN; ks++) {
            f16x8 B0 = bptr[0 * KSN * 64];
            f16x8 B1 = bptr[1 * KSN * 64];
            f16x8 B2 = bptr[2 * KSN * 64];
            f16x8 B3 = bptr[3 * KSN * 64];
            f16x8 A0 = *(const f16x8*)(aptr);
            f16x8 A1 = *(const f16x8*)(aptr + 16 * KROW);
            acc[0][0] = __builtin_amdgcn_mfma_f32_16x16x32_f16(A0, B0, acc[0][0], 0, 0, 0);
            acc[0][1] = __builtin_amdgcn_mfma_f32_16x16x32_f16(A0, B1, acc[0][1], 0, 0, 0);
            acc[0][2] = __builtin_amdgcn_mfma_f32_16x16x32_f16(A0, B2, acc[0][2], 0, 0, 0);
            acc[0][3] = __builtin_amdgcn_mfma_f32_16x16x32_f16(A0, B3, acc[0][3], 0, 0, 0);
            acc[1][0] = __builtin_amdgcn_mfma_f32_16x16x32_f16(A1, B0, acc[1][0], 0, 0, 0);
            acc[1][1] = __builtin_amdgcn_mfma_f32_16x16x32_f16(A1, B1, acc[1][1], 0, 0, 0);
            acc[1][2] = __builtin_amdgcn_mfma_f32_16x16x32_f16(A1, B2, acc[1][2], 0, 0, 0);
            acc[1][3] = __builtin_amdgcn_mfma_f32_16x16x32_f16(A1, B3, acc[1][3], 0, 0, 0);
            bptr += 64;
            aptr += 32;
        }

        // gate nonlinearities; C/D layout: col = lane&15, row = (lane>>4)*4 + reg
#pragma unroll
        for (int rt = 0; rt < 2; rt++) {
#pragma unroll
            for (int r = 0; r < 4; r++) {
                float ig = acc[rt][0][r];
                float fg = acc[rt][1][r];
                float gg = acc[rt][2][r];
                float og = acc[rt][3][r];
                const int ci = ji * 8 + rt * 4 + r;
                float cn = sigf(fg) * cacc[ci] + sigf(ig) * tanh_fast(gg);
                cacc[ci] = cn;
                if (WRITE_H) {
                    float hn = sigf(og) * tanh_fast(cn);
                    nxt[(rh * 32 + rt * 16 + kq * 4 + r) * KROW + j * 16 + m] =
                        (_Float16)hn;
                }
            }
        }
    }
}

__device__ __forceinline__ void xfill(_Float16* __restrict__ nxt,
                                      const _Float16* __restrict__ xlds,
                                      int step, int tid) {
    for (int i = tid; i < 64 * 11; i += NTHR) {
        int row = i / 11, xi = i - row * 11;
        nxt[row * KROW + 512 + xi] = xlds[row * 56 + step * 11 + xi];
    }
}

// ---------------- main persistent kernel ------------------------------------
__global__ __launch_bounds__(NTHR, 4)
void lstm_main(const float* __restrict__ ts,
               const _Float16* __restrict__ Wt,
               float* __restrict__ out) {
    extern __shared__ _Float16 smem[];
    _Float16* hbuf = smem;             // 2 buffers of [64][KROW]
    _Float16* xlds = smem + 2 * BUFH;  // [64][56] fp16 copy of ts rows
    const int tid  = threadIdx.x;
    const int lane = tid & 63;
    const int wave = tid >> 6;         // 0..15
    const int rh   = wave >> 3;        // row half 0/1
    const int wc   = wave & 7;         // col group 0..7
    const int b0   = blockIdx.x * ROWS;

    // zero both h buffers (covers h cols, x cols, bias, pad cols)
    {
        f16x8 z = {(_Float16)0, (_Float16)0, (_Float16)0, (_Float16)0,
                   (_Float16)0, (_Float16)0, (_Float16)0, (_Float16)0};
        for (int i = tid * 8; i < 2 * BUFH; i += NTHR * 8)
            *(f16x8*)(smem + i) = z;
    }
    // stage this block's time_series rows (coalesced) as fp16
    for (int i = tid; i < 64 * 55; i += NTHR) {
        int row = i / 55, e = i - row * 55;
        xlds[row * 56 + e] = (_Float16)ts[(size_t)(b0 + row) * 55 + e];
    }
    __syncthreads();
    // bias column (k=523) = 1.0 in both buffers; x_0 into buffer 0
    if (tid < 128) {
        int bsel = tid >> 6, row = tid & 63;
        hbuf[bsel * BUFH + row * KROW + 523] = (_Float16)1.0f;
    }
    for (int i = tid; i < 64 * 11; i += NTHR) {
        int row = i / 11, xi = i - row * 11;
        hbuf[row * KROW + 512 + xi] = xlds[row * 56 + xi];
    }
    __syncthreads();

    float cacc[32];
#pragma unroll
    for (int i = 0; i < 32; i++) cacc[i] = 0.0f;

    // t = 0: h == 0, only the x/bias K-step contributes
    run_step<16, true>(hbuf, hbuf + BUFH, Wt, cacc, rh, wc, lane);
    xfill(hbuf + BUFH, xlds, 1, tid);
    __syncthreads();

    for (int t = 1; t < 4; t++) {
        const _Float16* cur = hbuf + (t & 1) * BUFH;
        _Float16* nxt       = hbuf + ((t + 1) & 1) * BUFH;
        run_step<0, true>(cur, nxt, Wt, cacc, rh, wc, lane);
        xfill(nxt, xlds, t + 1, tid);
        __syncthreads();
    }
    // t = 4: no h write needed
    run_step<0, false>(hbuf, hbuf + BUFH, Wt, cacc, rh, wc, lane);

    // write final c
    const int m = lane & 15, kq = lane >> 4;
#pragma unroll
    for (int ji = 0; ji < 4; ji++) {
        const int j = wc + ji * 8;
#pragma unroll
        for (int rt = 0; rt < 2; rt++)
#pragma unroll
            for (int r = 0; r < 4; r++)
                out[(size_t)(b0 + rh * 32 + rt * 16 + kq * 4 + r) * HID + j * 16 + m] =
                    cacc[ji * 8 + rt * 4 + r];
    }
}

extern "C" void kernel_launch(void* const* d_in, const int* in_sizes, int n_in,
                              void* d_out, int out_size, void* d_ws, size_t ws_size,
                              hipStream_t stream) {
    const float* ts  = (const float*)d_in[0];
    const float* Wih = (const float*)d_in[1];
    const float* Whh = (const float*)d_in[2];
    const float* bih = (const float*)d_in[3];
    const float* bhh = (const float*)d_in[4];
    float* out       = (float*)d_out;
    _Float16* Wt     = (_Float16*)d_ws;   // 32*4*17 frags x 1 KB = 2,228,224 B

    (void)in_sizes; (void)n_in; (void)out_size; (void)ws_size;

    hipFuncSetAttribute(reinterpret_cast<const void*>(lstm_main),
                        hipFuncAttributeMaxDynamicSharedMemorySize, SMEM_BYTES);

    pack_w<<<544, 256, 0, stream>>>(Wih, Whh, bih, bhh, Wt);
    lstm_main<<<256, NTHR, SMEM_BYTES, stream>>>(ts, Wt, out);
}